// Round 1
// baseline (9.366 us; speedup 1.0000x reference)
//
#include <hip/hip_runtime.h>
#include <hip/hip_bf16.h>
#include <math.h>

#define K_SIZE 41

__global__ void FlatDilation1D_kernel(const float* __restrict__ in,
                                      const float* __restrict__ scale_p,
                                      float* __restrict__ out,
                                      int n, int start /* = -left, first index of padded window */) {
    __shared__ float f[K_SIZE];

    const float scale = scale_p[0];
    const int tid = threadIdx.x;

    if (tid < K_SIZE) {
        // f[tid] = max_j ( padded[(tid + j) % 41] + h[j] )
        float m = -INFINITY;
        #pragma unroll
        for (int j = 0; j < K_SIZE; ++j) {
            // h[j] = -((j-20)/scale)^16, exact repeated squaring in fp32
            float t  = (float)(j - 20) / scale;
            float t2  = t  * t;
            float t4  = t2 * t2;
            float t8  = t4 * t4;
            float t16 = t8 * t8;
            float h = -t16;

            int idx = tid + j;
            if (idx >= K_SIZE) idx -= K_SIZE;
            float v = in[start + idx] + h;
            m = fmaxf(m, v);
        }
        f[tid] = m;
    }
    __syncthreads();

    const int i = blockIdx.x * blockDim.x + threadIdx.x;
    if (i < n) {
        out[i] = f[i % K_SIZE];
    }
}

extern "C" void kernel_launch(void* const* d_in, const int* in_sizes, int n_in,
                              void* d_out, int out_size, void* d_ws, size_t ws_size,
                              hipStream_t stream) {
    const float* in      = (const float*)d_in[0];
    const float* scale_p = (const float*)d_in[1];
    float* out = (float*)d_out;

    const int n = in_sizes[0];

    // Reference: missing = K - n; left = missing//2 + 2 (Python floor div).
    // For n=8191: missing=-8150, missing//2=-4075, left=-4073 -> padded = in[4073:4114].
    const int missing = K_SIZE - n;
    int fd = missing / 2;
    if ((missing % 2 != 0) && (missing < 0)) fd -= 1;  // Python floor division
    const int left = fd + 2;
    const int start = -left;  // first element of the 41-wide window (left < 0 for n >> K)

    const int block = 256;
    const int grid = (n + block - 1) / block;
    FlatDilation1D_kernel<<<grid, block, 0, stream>>>(in, scale_p, out, n, start);
}